// Round 12
// baseline (43.706 us; speedup 1.0000x reference)
//
#include <hip/hip_runtime.h>

// Problem constants (from reference)
#define NQ 6
#define NF 4
#define GG 14
#define GG2 196
#define GG3 2744
#define NSIDE 12
#define PP 1728          // NSIDE^3
#define NC 40
#define BB 16
#define LAM 0.1f
#define FEAT_LEN (NF*PP*NQ)   // 41472
#define KCH 256
#define NCHUNK 162            // 41472 / 256
#define CTILES 5              // 40 / 8
#define NWAVE_IP2 (3456*4)    // 13824 = 128*108
#define NENC (PP*BB*NQ)       // 165888 composed encoding columns

__device__ __forceinline__ float ang(const float* xp, int i) {
    return xp[(i/9)*GG2 + ((i/3)%3)*GG + (i%3)];
}

// ---------- precompute: all trig (encoding columns + CRot matrices) ----------
// enc[((p*BB+b)*NQ+q)] = composed first column (c0r,c0i,c1r,c1i) of qubit q's
// encoding unitary (gate q, then gate q+6 if q<3). crotU[f*NQ+i][8] = full 2x2.

__global__ __launch_bounds__(256) void precomp_kernel(
    const float* __restrict__ x, const float* __restrict__ theta,
    float* __restrict__ enc, float* __restrict__ crotU)
{
    const int j = blockIdx.x * 256 + threadIdx.x;
    if (j < NENC) {
        const int q  = j % NQ;
        const int pb = j / NQ;
        const int b  = pb % BB;
        const int p  = pb / BB;
        const int px = p/(NSIDE*NSIDE), py = (p/NSIDE)%NSIDE, pz = p%NSIDE;
        const float* xp = x + (size_t)b*GG3 + px*GG2 + py*GG + pz;
        float phi = ang(xp,3*q), th = ang(xp,3*q+1), om = ang(xp,3*q+2);
        float s, cc, sap, cap, sam, cam;
        __sincosf(0.5f*th, &s, &cc);
        __sincosf(0.5f*(phi+om), &sap, &cap);
        __sincosf(0.5f*(phi-om), &sam, &cam);
        float c0r = cap*cc, c0i = -sap*cc, c1r = cam*s, c1i = -sam*s;
        if (q < 3) {   // compose with gate q+6 (applied second)
            const int k2 = 3*(q+6);
            float phi2 = ang(xp,k2), th2 = ang(xp,k2+1), om2 = ang(xp,k2+2);
            float s_,c_,sap_,cap_,sam_,cam_;
            __sincosf(0.5f*th2, &s_, &c_);
            __sincosf(0.5f*(phi2+om2), &sap_, &cap_);
            __sincosf(0.5f*(phi2-om2), &sam_, &cam_);
            float b00r=cap_*c_, b00i=-sap_*c_, b01r=-cam_*s_, b01i=-sam_*s_;
            float b10r=cam_*s_, b10i=-sam_*s_, b11r=cap_*c_,  b11i= sap_*c_;
            float n0r = b00r*c0r - b00i*c0i + b01r*c1r - b01i*c1i;
            float n0i = b00r*c0i + b00i*c0r + b01r*c1i + b01i*c1r;
            float n1r = b10r*c0r - b10i*c0i + b11r*c1r - b11i*c1i;
            float n1i = b10r*c0i + b10i*c0r + b11r*c1i + b11i*c1r;
            c0r=n0r; c0i=n0i; c1r=n1r; c1i=n1i;
        }
        *(float4*)(enc + 4*(size_t)j) = make_float4(c0r, c0i, c1r, c1i);
    } else if (j < NENC + NF*NQ) {
        const int k = j - NENC;
        const float* a = theta + k*3;
        float s, cc, sap, cap, sam, cam;
        __sincosf(0.5f*a[1], &s, &cc);
        __sincosf(0.5f*(a[0]+a[2]), &sap, &cap);
        __sincosf(0.5f*(a[0]-a[2]), &sam, &cam);
        float* o = crotU + k*8;
        o[0] =  cap*cc; o[1] = -sap*cc;
        o[2] = -cam*s;  o[3] = -sam*s;
        o[4] =  cam*s;  o[5] = -sam*s;
        o[6] =  cap*cc; o[7] =  sap*cc;
    }
}

// ---------- sim: 8 lanes per circuit, 8 complex amps per lane; NO LDS/barrier ----------
// lane = f*16 + g*2 + c ; g bits = state bits [5:3] (g0<->q2, g1<->q1, g2<->q0);
// local amp l bits = state bits [2:0] (bit2<->q3, bit1<->q4, bit0<->q5).
// block = 256 thr = 4 waves; p = blockIdx>>1, bh = blockIdx&1, b = bh*8+w*2+c.

__global__ __launch_bounds__(256) void sim_kernel(
    const float* __restrict__ enc,    // [PP*BB*NQ][4]
    const float* __restrict__ crotU,  // [24][8]
    float* __restrict__ feats,        // [B][NF][PP][NQ]
    float* __restrict__ ip2)          // [NWAVE_IP2]
{
    const int t = threadIdx.x;
    const int w = t >> 6, lane = t & 63;
    const int c  = lane & 1;
    const int g0 = (lane >> 1) & 1, g1 = (lane >> 2) & 1, g2 = (lane >> 3) & 1;
    const int f  = (lane >> 4) & 3;
    const int p  = blockIdx.x >> 1;
    const int bh = blockIdx.x & 1;
    const int b  = bh*8 + w*2 + c;

    const float4* encp = (const float4*)enc + ((size_t)p*BB + b)*NQ;
    const float4* crp  = (const float4*)crotU + f*NQ*2;

    // ---- encoding: product state. Lane prefactor from qubits 0,1,2;
    // local 8-amp tensor ladder from qubits 3,4,5.
    float ar[8], ai[8];
    {
        float4 C0 = encp[0], C1 = encp[1], C2 = encp[2];
        float e0r = g2 ? C0.z : C0.x, e0i = g2 ? C0.w : C0.y;
        float e1r = g1 ? C1.z : C1.x, e1i = g1 ? C1.w : C1.y;
        float e2r = g0 ? C2.z : C2.x, e2i = g0 ? C2.w : C2.y;
        float t01r = e0r*e1r - e0i*e1i, t01i = e0r*e1i + e0i*e1r;
        float pfr = t01r*e2r - t01i*e2i, pfi = t01r*e2i + t01i*e2r;
        float4 C3 = encp[3], C4 = encp[4], C5 = encp[5];
        ar[4] = C3.z*pfr - C3.w*pfi;  ai[4] = C3.z*pfi + C3.w*pfr;
        ar[0] = C3.x*pfr - C3.y*pfi;  ai[0] = C3.x*pfi + C3.y*pfr;
        #pragma unroll
        for (int l = 0; l <= 4; l += 4) {
            float r0 = ar[l], i0 = ai[l];
            ar[l+2] = C4.z*r0 - C4.w*i0;  ai[l+2] = C4.z*i0 + C4.w*r0;
            ar[l]   = C4.x*r0 - C4.y*i0;  ai[l]   = C4.x*i0 + C4.y*r0;
        }
        #pragma unroll
        for (int l = 0; l <= 6; l += 2) {
            float r0 = ar[l], i0 = ai[l];
            ar[l+1] = C5.z*r0 - C5.w*i0;  ai[l+1] = C5.z*i0 + C5.w*r0;
            ar[l]   = C5.x*r0 - C5.y*i0;  ai[l]   = C5.x*i0 + C5.y*r0;
        }
    }

    // ---- CRot ring for feature f (ctrl i -> tgt (i+1)%6)
    // CR0: ctrl q0(g2), tgt q1(g1) -> cross lane-xor 4
    {
        float4 A = crp[0], Bq = crp[1];
        float cAr = g1 ? Bq.z : A.x, cAi = g1 ? Bq.w : A.y;
        float cBr = g1 ? Bq.x : A.z, cBi = g1 ? Bq.y : A.w;
        if (!g2) { cAr = 1.f; cAi = 0.f; cBr = 0.f; cBi = 0.f; }
        #pragma unroll
        for (int l = 0; l < 8; ++l) {
            float prr = __shfl_xor(ar[l], 4), pri = __shfl_xor(ai[l], 4);
            float nr = cAr*ar[l] - cAi*ai[l] + cBr*prr - cBi*pri;
            float ni = cAr*ai[l] + cAi*ar[l] + cBr*pri + cBi*prr;
            ar[l] = nr; ai[l] = ni;
        }
    }
    // CR1: ctrl q1(g1), tgt q2(g0) -> cross lane-xor 2
    {
        float4 A = crp[2], Bq = crp[3];
        float cAr = g0 ? Bq.z : A.x, cAi = g0 ? Bq.w : A.y;
        float cBr = g0 ? Bq.x : A.z, cBi = g0 ? Bq.y : A.w;
        if (!g1) { cAr = 1.f; cAi = 0.f; cBr = 0.f; cBi = 0.f; }
        #pragma unroll
        for (int l = 0; l < 8; ++l) {
            float prr = __shfl_xor(ar[l], 2), pri = __shfl_xor(ai[l], 2);
            float nr = cAr*ar[l] - cAi*ai[l] + cBr*prr - cBi*pri;
            float ni = cAr*ai[l] + cAi*ar[l] + cBr*pri + cBi*prr;
            ar[l] = nr; ai[l] = ni;
        }
    }
    // CR2: ctrl q2(g0), tgt q3(local mask4): identity coeffs when !g0
    {
        float4 A = crp[4], Bq = crp[5];
        if (!g0) { A = make_float4(1.f,0.f,0.f,0.f); Bq = make_float4(0.f,0.f,1.f,0.f); }
        #pragma unroll
        for (int l = 0; l < 4; ++l) {
            const int l1 = l + 4;
            float a0r=ar[l], a0i=ai[l], a1r=ar[l1], a1i=ai[l1];
            ar[l]  = A.x*a0r - A.y*a0i + A.z*a1r - A.w*a1i;
            ai[l]  = A.x*a0i + A.y*a0r + A.z*a1i + A.w*a1r;
            ar[l1] = Bq.x*a0r - Bq.y*a0i + Bq.z*a1r - Bq.w*a1i;
            ai[l1] = Bq.x*a0i + Bq.y*a0r + Bq.z*a1i + Bq.w*a1r;
        }
    }
    // CR3: ctrl q3(bit2), tgt q4(bit1): pairs (4,6),(5,7)
    {
        float4 A = crp[6], Bq = crp[7];
        #pragma unroll
        for (int l = 4; l < 6; ++l) {
            const int l1 = l + 2;
            float a0r=ar[l], a0i=ai[l], a1r=ar[l1], a1i=ai[l1];
            ar[l]  = A.x*a0r - A.y*a0i + A.z*a1r - A.w*a1i;
            ai[l]  = A.x*a0i + A.y*a0r + A.z*a1i + A.w*a1r;
            ar[l1] = Bq.x*a0r - Bq.y*a0i + Bq.z*a1r - Bq.w*a1i;
            ai[l1] = Bq.x*a0i + Bq.y*a0r + Bq.z*a1i + Bq.w*a1r;
        }
    }
    // CR4: ctrl q4(bit1), tgt q5(bit0): pairs (2,3),(6,7)
    {
        float4 A = crp[8], Bq = crp[9];
        #pragma unroll
        for (int l = 2; l < 8; l += 4) {
            const int l1 = l + 1;
            float a0r=ar[l], a0i=ai[l], a1r=ar[l1], a1i=ai[l1];
            ar[l]  = A.x*a0r - A.y*a0i + A.z*a1r - A.w*a1i;
            ai[l]  = A.x*a0i + A.y*a0r + A.z*a1i + A.w*a1r;
            ar[l1] = Bq.x*a0r - Bq.y*a0i + Bq.z*a1r - Bq.w*a1i;
            ai[l1] = Bq.x*a0i + Bq.y*a0r + Bq.z*a1i + Bq.w*a1r;
        }
    }
    // CR5: ctrl q5(bit0 -> odd l), tgt q0(g2) -> cross lane-xor 8
    {
        float4 A = crp[10], Bq = crp[11];
        float cAr = g2 ? Bq.z : A.x, cAi = g2 ? Bq.w : A.y;
        float cBr = g2 ? Bq.x : A.z, cBi = g2 ? Bq.y : A.w;
        #pragma unroll
        for (int l = 1; l < 8; l += 2) {
            float prr = __shfl_xor(ar[l], 8), pri = __shfl_xor(ai[l], 8);
            float nr = cAr*ar[l] - cAi*ai[l] + cBr*prr - cBi*pri;
            float ni = cAr*ai[l] + cAi*ar[l] + cBr*pri + cBi*prr;
            ar[l] = nr; ai[l] = ni;
        }
    }

    // ---- probabilities
    float pr[8];
    #pragma unroll
    for (int l = 0; l < 8; ++l) pr[l] = ar[l]*ar[l] + ai[l]*ai[l];

    // ---- loss pair-dots: f-partners at lane-xor 16,32,48; g-reduce xor 2,4,8
    float lc = 0.f;
    #pragma unroll
    for (int xi = 0; xi < 3; ++xi) {
        const int xm = (xi + 1) << 4;
        float d = 0.f;
        #pragma unroll
        for (int l = 0; l < 8; ++l) d += pr[l] * __shfl_xor(pr[l], xm);
        d += __shfl_xor(d, 2);
        d += __shfl_xor(d, 4);
        d += __shfl_xor(d, 8);
        lc += d*d;
    }
    #pragma unroll
    for (int m = 1; m < 64; m <<= 1) lc += __shfl_xor(lc, m);
    if (lane == 0) ip2[blockIdx.x*4 + w] = lc;   // 8x-counted; finalize /8

    // ---- expvals
    float e3 = (pr[0]+pr[1]+pr[2]+pr[3]) - (pr[4]+pr[5]+pr[6]+pr[7]);
    float e4 = (pr[0]+pr[1]+pr[4]+pr[5]) - (pr[2]+pr[3]+pr[6]+pr[7]);
    float e5 = (pr[0]+pr[2]+pr[4]+pr[6]) - (pr[1]+pr[3]+pr[5]+pr[7]);
    float s  = (pr[0]+pr[1]+pr[2]+pr[3]) + (pr[4]+pr[5]+pr[6]+pr[7]);
    float e0 = g2 ? -s : s;
    float e1 = g1 ? -s : s;
    float e2 = g0 ? -s : s;
    #define GRED(e) { e += __shfl_xor(e, 2); e += __shfl_xor(e, 4); e += __shfl_xor(e, 8); }
    GRED(e0) GRED(e1) GRED(e2) GRED(e3) GRED(e4) GRED(e5)
    #undef GRED

    if (((lane >> 1) & 7) == 0) {     // one lane per (c,f)
        float* fo = feats + (((size_t)b*NF + f)*PP + p)*NQ;
        fo[0]=e0; fo[1]=e1; fo[2]=e2; fo[3]=e3; fo[4]=e4; fo[5]=e5;
    }
}

// ---------- logits phase A: K-split (finer: 162 chunks), W read once ----------

__global__ __launch_bounds__(128) void logitsA(
    const float* __restrict__ feats,   // [BB][FEAT_LEN]
    const float* __restrict__ W,       // [NC][FEAT_LEN]
    float* __restrict__ partial)       // [NCHUNK][BB][NC]
{
    const int chunk = blockIdx.x;      // 0..161
    const int ctile = blockIdx.y;      // 0..4
    const int t = threadIdx.x;         // 128
    const int jbase = chunk * KCH;

    __shared__ __align__(16) float fs[BB][KCH + 4];

    #pragma unroll
    for (int i = 0; i < 8; ++i) {
        const int gi = i*128 + t;      // 0..1023 float4 (64 per row)
        const int br = gi >> 6;
        const int c4 = gi & 63;
        float4 v = *(const float4*)(feats + (size_t)br*FEAT_LEN + jbase + c4*4);
        *(float4*)&fs[br][c4*4] = v;
    }
    __syncthreads();

    const int cl = t >> 4, b = t & 15;
    const int c = ctile*8 + cl;
    const float* wr = W + (size_t)c*FEAT_LEN + jbase;
    float acc = 0.f;
    #pragma unroll 8
    for (int j4 = 0; j4 < KCH/4; ++j4) {
        float4 wv = *(const float4*)(wr + j4*4);
        float4 fv = *(const float4*)&fs[b][j4*4];
        acc += wv.x*fv.x + wv.y*fv.y + wv.z*fv.z + wv.w*fv.w;
    }
    partial[((size_t)chunk*BB + b)*NC + c] = acc;
}

// ---------- phase B: logits reduce + bias (coalesced), loss reduce (unrolled) ----------

__global__ __launch_bounds__(768) void finalize_kernel(
    const float* __restrict__ partial, const float* __restrict__ bias,
    const float* __restrict__ ip2, float* __restrict__ out)
{
    const int t = threadIdx.x;
    __shared__ float red[2];

    if (t >= 640) {
        const int idx = t - 640;       // 128 threads, 108 strided loads each
        float acc = 0.f;
        #pragma unroll
        for (int k = 0; k < 108; ++k) acc += ip2[idx + k*128];
        #pragma unroll
        for (int m = 1; m < 64; m <<= 1) acc += __shfl_xor(acc, m);
        if ((idx & 63) == 0) red[idx >> 6] = acc;
    }
    __syncthreads();

    if (t < BB*NC) {
        const int b = t / NC, c = t % NC;   // consecutive t -> consecutive c
        float acc = bias[c];
        #pragma unroll
        for (int i = 0; i < NCHUNK; ++i)
            acc += partial[((size_t)i*BB + b)*NC + c];
        out[t] = acc;
    } else if (t == 640) {
        out[BB*NC] = (red[0] + red[1]) *
                     (LAM / (float)(NF*(NF-1)) / (float)BB * 0.125f);
    }
}

extern "C" void kernel_launch(void* const* d_in, const int* in_sizes, int n_in,
                              void* d_out, int out_size, void* d_ws, size_t ws_size,
                              hipStream_t stream) {
    const float* x     = (const float*)d_in[0];  // [16,14,14,14]
    const float* theta = (const float*)d_in[1];  // [4,1,6,3]
    const float* W     = (const float*)d_in[2];  // [40,41472]
    const float* bias  = (const float*)d_in[3];  // [40]
    float* out = (float*)d_out;                  // [640 logits][1 loss]

    float* feats   = (float*)d_ws;                       // BB*FEAT_LEN
    float* ip2     = feats + (size_t)BB * FEAT_LEN;      // NWAVE_IP2
    float* partial = ip2 + NWAVE_IP2;                    // NCHUNK*BB*NC
    float* enc     = partial + (size_t)NCHUNK*BB*NC;     // NENC*4
    float* crotU   = enc + (size_t)NENC*4;               // 192

    precomp_kernel<<<(NENC + NF*NQ + 255)/256, 256, 0, stream>>>(x, theta, enc, crotU);
    sim_kernel<<<2*PP, 256, 0, stream>>>(enc, crotU, feats, ip2);
    logitsA<<<dim3(NCHUNK, CTILES), 128, 0, stream>>>(feats, W, partial);
    finalize_kernel<<<1, 768, 0, stream>>>(partial, bias, ip2, out);
}

// Round 13
// 38.027 us; speedup vs baseline: 1.1493x; 1.1493x over previous
//
#include <hip/hip_runtime.h>

// Problem constants (from reference)
#define NQ 6
#define NF 4
#define GG 14
#define GG2 196
#define GG3 2744
#define NSIDE 12
#define PP 1728          // NSIDE^3
#define NC 40
#define BB 16
#define LAM 0.1f
#define FEAT_LEN (NF*PP*NQ)   // 41472
#define KCH 512
#define NCHUNK 81             // 41472 / 512
#define CTILES 5              // 40 / 8
#define NWAVE_IP2 (3456*4)    // 13824 = 128*108

template<int CTRL>
__device__ __forceinline__ float fdpp(float v) {
    return __int_as_float(__builtin_amdgcn_mov_dpp(__float_as_int(v), CTRL, 0xF, 0xF, true));
}
#define DPP1(v) fdpp<0xB1>(v)   // quad_perm xor1 (VALU)
#define DPP2(v) fdpp<0x4E>(v)   // quad_perm xor2 (VALU)

// ---------- sim: 8 lanes per circuit, 8 complex amps per lane ----------
// lane = [b5=c][b4b3=f][b2=q0][b1=q4][b0=q2] ; reg l = [bit2=q1][bit1=q3][bit0=q5]
// CR ring: CR0/CR2/CR4 local (lane-selected), CR1=xor1(DPP), CR3=xor2(DPP),
// CR5=xor4 (only DS shuffle among gates).
// block = 256 thr = 4 waves; p = blockIdx>>1, bh = blockIdx&1, b = bh*8+w*2+c.

__global__ __launch_bounds__(256) void sim_kernel(
    const float* __restrict__ x,      // [B,14,14,14]
    const float* __restrict__ theta,  // [NF,1,6,3]
    float* __restrict__ feats,        // [B][NF][PP][NQ]
    float* __restrict__ ip2)          // [NWAVE_IP2]
{
    const int t = threadIdx.x;
    const int w = t >> 6, lane = t & 63;
    const int c   = lane >> 5;
    const int f   = (lane >> 3) & 3;
    const int gq0 = (lane >> 2) & 1;
    const int gq4 = (lane >> 1) & 1;
    const int gq2 = lane & 1;
    const int p  = blockIdx.x >> 1;
    const int bh = blockIdx.x & 1;
    const int b  = bh*8 + w*2 + c;
    const int bl = w*2 + c;           // local batch index 0..7

    __shared__ __align__(16) float scrot[NF*NQ][8];   // 24 CRot 2x2 matrices
    __shared__ __align__(16) float scomp[8][NQ][4];   // composed enc columns

    const int px = p/(NSIDE*NSIDE), py = (p/NSIDE)%NSIDE, pz = p%NSIDE;

    // threads 64..87: CRot matrices (block-invariant)
    if (t >= 64 && t < 64 + NF*NQ) {
        const int j = t - 64;
        const float* a = theta + j*3;
        float s, cc, sap, cap, sam, cam;
        __sincosf(0.5f*a[1], &s, &cc);
        __sincosf(0.5f*(a[0]+a[2]), &sap, &cap);
        __sincosf(0.5f*(a[0]-a[2]), &sam, &cam);
        scrot[j][0] =  cap*cc; scrot[j][1] = -sap*cc;
        scrot[j][2] = -cam*s;  scrot[j][3] = -sam*s;
        scrot[j][4] =  cam*s;  scrot[j][5] = -sam*s;
        scrot[j][6] =  cap*cc; scrot[j][7] =  sap*cc;
    }
    // threads 0..47: composed encoding columns for (bl2, q)
    if (t < 8*NQ) {
        const int bl2 = t / NQ, q = t % NQ;
        const int b2 = bh*8 + bl2;
        const float* xp = x + (size_t)b2*GG3 + px*GG2 + py*GG + pz;
        #define SPV(i) xp[((i)/9)*GG2 + (((i)/3)%3)*GG + ((i)%3)]
        float s, cc, sap, cap, sam, cam;
        __sincosf(0.5f*SPV(3*q+1), &s, &cc);
        __sincosf(0.5f*(SPV(3*q)+SPV(3*q+2)), &sap, &cap);
        __sincosf(0.5f*(SPV(3*q)-SPV(3*q+2)), &sam, &cam);
        float c0r = cap*cc, c0i = -sap*cc, c1r = cam*s, c1i = -sam*s;
        if (q < 3) {   // compose with gate q+6 (applied second)
            const int k2 = 3*(q+6);
            float s_,c_,sap_,cap_,sam_,cam_;
            __sincosf(0.5f*SPV(k2+1), &s_, &c_);
            __sincosf(0.5f*(SPV(k2)+SPV(k2+2)), &sap_, &cap_);
            __sincosf(0.5f*(SPV(k2)-SPV(k2+2)), &sam_, &cam_);
            float b00r=cap_*c_, b00i=-sap_*c_, b01r=-cam_*s_, b01i=-sam_*s_;
            float b10r=cam_*s_, b10i=-sam_*s_, b11r=cap_*c_,  b11i= sap_*c_;
            float n0r = b00r*c0r - b00i*c0i + b01r*c1r - b01i*c1i;
            float n0i = b00r*c0i + b00i*c0r + b01r*c1i + b01i*c1r;
            float n1r = b10r*c0r - b10i*c0i + b11r*c1r - b11i*c1i;
            float n1i = b10r*c0i + b10i*c0r + b11r*c1i + b11i*c1r;
            c0r=n0r; c0i=n0i; c1r=n1r; c1i=n1i;
        }
        #undef SPV
        scomp[bl2][q][0]=c0r; scomp[bl2][q][1]=c0i;
        scomp[bl2][q][2]=c1r; scomp[bl2][q][3]=c1i;
    }
    __syncthreads();

    // ---- encoding: product state. Prefactor from q0,q2,q4 (lane bits);
    // reg ladder from q1 (bit2), q3 (bit1), q5 (bit0).
    float ar[8], ai[8];
    {
        float4 C0 = *(const float4*)&scomp[bl][0][0];
        float4 C2 = *(const float4*)&scomp[bl][2][0];
        float4 C4 = *(const float4*)&scomp[bl][4][0];
        float e0r = gq0 ? C0.z : C0.x, e0i = gq0 ? C0.w : C0.y;
        float e2r = gq2 ? C2.z : C2.x, e2i = gq2 ? C2.w : C2.y;
        float e4r = gq4 ? C4.z : C4.x, e4i = gq4 ? C4.w : C4.y;
        float t02r = e0r*e2r - e0i*e2i, t02i = e0r*e2i + e0i*e2r;
        float pfr = t02r*e4r - t02i*e4i, pfi = t02r*e4i + t02i*e4r;
        float4 C1 = *(const float4*)&scomp[bl][1][0];
        float4 C3 = *(const float4*)&scomp[bl][3][0];
        float4 C5 = *(const float4*)&scomp[bl][5][0];
        // q1 spread (reg bit2) from {0}
        ar[4] = C1.z*pfr - C1.w*pfi;  ai[4] = C1.z*pfi + C1.w*pfr;
        ar[0] = C1.x*pfr - C1.y*pfi;  ai[0] = C1.x*pfi + C1.y*pfr;
        // q3 spread (reg bit1) on {0,4}
        #pragma unroll
        for (int l = 0; l <= 4; l += 4) {
            float r0 = ar[l], i0 = ai[l];
            ar[l+2] = C3.z*r0 - C3.w*i0;  ai[l+2] = C3.z*i0 + C3.w*r0;
            ar[l]   = C3.x*r0 - C3.y*i0;  ai[l]   = C3.x*i0 + C3.y*r0;
        }
        // q5 spread (reg bit0) on {0,2,4,6}
        #pragma unroll
        for (int l = 0; l <= 6; l += 2) {
            float r0 = ar[l], i0 = ai[l];
            ar[l+1] = C5.z*r0 - C5.w*i0;  ai[l+1] = C5.z*i0 + C5.w*r0;
            ar[l]   = C5.x*r0 - C5.y*i0;  ai[l]   = C5.x*i0 + C5.y*r0;
        }
    }

    const float4* crp = (const float4*)&scrot[f*NQ][0];

    // CR0: ctrl q0(lane b2), tgt q1(reg bit2): local pairs (l,l+4); identity if !gq0
    {
        float4 A = crp[0], Bq = crp[1];
        if (!gq0) { A = make_float4(1.f,0.f,0.f,0.f); Bq = make_float4(0.f,0.f,1.f,0.f); }
        #pragma unroll
        for (int l = 0; l < 4; ++l) {
            const int l1 = l + 4;
            float a0r=ar[l], a0i=ai[l], a1r=ar[l1], a1i=ai[l1];
            ar[l]  = A.x*a0r - A.y*a0i + A.z*a1r - A.w*a1i;
            ai[l]  = A.x*a0i + A.y*a0r + A.z*a1i + A.w*a1r;
            ar[l1] = Bq.x*a0r - Bq.y*a0i + Bq.z*a1r - Bq.w*a1i;
            ai[l1] = Bq.x*a0i + Bq.y*a0r + Bq.z*a1i + Bq.w*a1r;
        }
    }
    // CR1: ctrl q1(reg bit2 -> l=4..7), tgt q2(lane b0) -> DPP xor1
    {
        float4 A = crp[2], Bq = crp[3];
        float cAr = gq2 ? Bq.z : A.x, cAi = gq2 ? Bq.w : A.y;
        float cBr = gq2 ? Bq.x : A.z, cBi = gq2 ? Bq.y : A.w;
        #pragma unroll
        for (int l = 4; l < 8; ++l) {
            float prr = DPP1(ar[l]), pri = DPP1(ai[l]);
            float nr = cAr*ar[l] - cAi*ai[l] + cBr*prr - cBi*pri;
            float ni = cAr*ai[l] + cAi*ar[l] + cBr*pri + cBi*prr;
            ar[l] = nr; ai[l] = ni;
        }
    }
    // CR2: ctrl q2(lane b0), tgt q3(reg bit1): pairs (l,l+2), identity if !gq2
    {
        float4 A = crp[4], Bq = crp[5];
        if (!gq2) { A = make_float4(1.f,0.f,0.f,0.f); Bq = make_float4(0.f,0.f,1.f,0.f); }
        #pragma unroll
        for (int li = 0; li < 4; ++li) {
            const int l = (li & 1) | ((li & 2) << 1);   // 0,1,4,5
            const int l1 = l + 2;
            float a0r=ar[l], a0i=ai[l], a1r=ar[l1], a1i=ai[l1];
            ar[l]  = A.x*a0r - A.y*a0i + A.z*a1r - A.w*a1i;
            ai[l]  = A.x*a0i + A.y*a0r + A.z*a1i + A.w*a1r;
            ar[l1] = Bq.x*a0r - Bq.y*a0i + Bq.z*a1r - Bq.w*a1i;
            ai[l1] = Bq.x*a0i + Bq.y*a0r + Bq.z*a1i + Bq.w*a1r;
        }
    }
    // CR3: ctrl q3(reg bit1 -> l in {2,3,6,7}), tgt q4(lane b1) -> DPP xor2
    {
        float4 A = crp[6], Bq = crp[7];
        float cAr = gq4 ? Bq.z : A.x, cAi = gq4 ? Bq.w : A.y;
        float cBr = gq4 ? Bq.x : A.z, cBi = gq4 ? Bq.y : A.w;
        #pragma unroll
        for (int li = 0; li < 4; ++li) {
            const int l = 2 + (li & 1) + ((li & 2) << 1);   // 2,3,6,7
            float prr = DPP2(ar[l]), pri = DPP2(ai[l]);
            float nr = cAr*ar[l] - cAi*ai[l] + cBr*prr - cBi*pri;
            float ni = cAr*ai[l] + cAi*ar[l] + cBr*pri + cBi*prr;
            ar[l] = nr; ai[l] = ni;
        }
    }
    // CR4: ctrl q4(lane b1), tgt q5(reg bit0): pairs (l,l+1), identity if !gq4
    {
        float4 A = crp[8], Bq = crp[9];
        if (!gq4) { A = make_float4(1.f,0.f,0.f,0.f); Bq = make_float4(0.f,0.f,1.f,0.f); }
        #pragma unroll
        for (int l = 0; l < 8; l += 2) {
            const int l1 = l + 1;
            float a0r=ar[l], a0i=ai[l], a1r=ar[l1], a1i=ai[l1];
            ar[l]  = A.x*a0r - A.y*a0i + A.z*a1r - A.w*a1i;
            ai[l]  = A.x*a0i + A.y*a0r + A.z*a1i + A.w*a1r;
            ar[l1] = Bq.x*a0r - Bq.y*a0i + Bq.z*a1r - Bq.w*a1i;
            ai[l1] = Bq.x*a0i + Bq.y*a0r + Bq.z*a1i + Bq.w*a1r;
        }
    }
    // CR5: ctrl q5(reg bit0 -> odd l), tgt q0(lane b2) -> shfl xor4 (DS)
    {
        float4 A = crp[10], Bq = crp[11];
        float cAr = gq0 ? Bq.z : A.x, cAi = gq0 ? Bq.w : A.y;
        float cBr = gq0 ? Bq.x : A.z, cBi = gq0 ? Bq.y : A.w;
        #pragma unroll
        for (int l = 1; l < 8; l += 2) {
            float prr = __shfl_xor(ar[l], 4), pri = __shfl_xor(ai[l], 4);
            float nr = cAr*ar[l] - cAi*ai[l] + cBr*prr - cBi*pri;
            float ni = cAr*ai[l] + cAi*ar[l] + cBr*pri + cBi*prr;
            ar[l] = nr; ai[l] = ni;
        }
    }

    // ---- probabilities
    float pr[8];
    #pragma unroll
    for (int l = 0; l < 8; ++l) pr[l] = ar[l]*ar[l] + ai[l]*ai[l];

    // ---- loss pair-dots: f-partners at lane-xor 8,16,24; g-reduce xor1,2,4
    float lc = 0.f;
    #pragma unroll
    for (int xi = 1; xi <= 3; ++xi) {
        const int xm = xi << 3;
        float d = 0.f;
        #pragma unroll
        for (int l = 0; l < 8; ++l) d += pr[l] * __shfl_xor(pr[l], xm);
        d += DPP1(d);
        d += DPP2(d);
        d += __shfl_xor(d, 4);
        lc += d*d;
    }
    lc += DPP1(lc);
    lc += DPP2(lc);
    lc += __shfl_xor(lc, 4);
    lc += __shfl_xor(lc, 8);
    lc += __shfl_xor(lc, 16);
    lc += __shfl_xor(lc, 32);
    if (lane == 0) ip2[blockIdx.x*4 + w] = lc;   // 8x-counted; finalize /8

    // ---- expvals: reg-local signed sums (q1,q3,q5), lane signs (q0,q2,q4)
    float eq1 = (pr[0]+pr[1]+pr[2]+pr[3]) - (pr[4]+pr[5]+pr[6]+pr[7]);
    float eq3 = (pr[0]+pr[1]+pr[4]+pr[5]) - (pr[2]+pr[3]+pr[6]+pr[7]);
    float eq5 = (pr[0]+pr[2]+pr[4]+pr[6]) - (pr[1]+pr[3]+pr[5]+pr[7]);
    float s   = (pr[0]+pr[1]+pr[2]+pr[3]) + (pr[4]+pr[5]+pr[6]+pr[7]);
    float eq0 = gq0 ? -s : s;
    float eq2 = gq2 ? -s : s;
    float eq4 = gq4 ? -s : s;
    #define GRED(e) { e += DPP1(e); e += DPP2(e); e += __shfl_xor(e, 4); }
    GRED(eq0) GRED(eq1) GRED(eq2) GRED(eq3) GRED(eq4) GRED(eq5)
    #undef GRED

    if ((lane & 7) == 0) {            // one lane per (c,f)
        float* fo = feats + (((size_t)b*NF + f)*PP + p)*NQ;
        fo[0]=eq0; fo[1]=eq1; fo[2]=eq2; fo[3]=eq3; fo[4]=eq4; fo[5]=eq5;
    }
}

// ---------- logits phase A: K-split, W read once ----------

__global__ __launch_bounds__(128) void logitsA(
    const float* __restrict__ feats,   // [BB][FEAT_LEN]
    const float* __restrict__ W,       // [NC][FEAT_LEN]
    float* __restrict__ partial)       // [NCHUNK][BB][NC]
{
    const int chunk = blockIdx.x;      // 0..80
    const int ctile = blockIdx.y;      // 0..4
    const int t = threadIdx.x;         // 128
    const int jbase = chunk * KCH;

    __shared__ __align__(16) float fs[BB][KCH + 4];

    #pragma unroll
    for (int i = 0; i < 16; ++i) {
        const int gi = i*128 + t;
        const int br = gi >> 7;
        const int c4 = gi & 127;
        float4 v = *(const float4*)(feats + (size_t)br*FEAT_LEN + jbase + c4*4);
        *(float4*)&fs[br][c4*4] = v;
    }
    __syncthreads();

    const int cl = t >> 4, b = t & 15;
    const int c = ctile*8 + cl;
    const float* wr = W + (size_t)c*FEAT_LEN + jbase;
    float acc = 0.f;
    #pragma unroll 8
    for (int j4 = 0; j4 < KCH/4; ++j4) {
        float4 wv = *(const float4*)(wr + j4*4);
        float4 fv = *(const float4*)&fs[b][j4*4];
        acc += wv.x*fv.x + wv.y*fv.y + wv.z*fv.z + wv.w*fv.w;
    }
    partial[((size_t)chunk*BB + b)*NC + c] = acc;
}

// ---------- phase B: logits reduce + bias (coalesced), loss reduce (unrolled) ----------

__global__ __launch_bounds__(768) void finalize_kernel(
    const float* __restrict__ partial, const float* __restrict__ bias,
    const float* __restrict__ ip2, float* __restrict__ out)
{
    const int t = threadIdx.x;
    __shared__ float red[2];

    if (t >= 640) {
        const int idx = t - 640;       // 128 threads, 108 strided loads each
        float acc = 0.f;
        #pragma unroll
        for (int k = 0; k < 108; ++k) acc += ip2[idx + k*128];
        #pragma unroll
        for (int m = 1; m < 64; m <<= 1) acc += __shfl_xor(acc, m);
        if ((idx & 63) == 0) red[idx >> 6] = acc;
    }
    __syncthreads();

    if (t < BB*NC) {
        const int b = t / NC, c = t % NC;   // consecutive t -> consecutive c
        float acc = bias[c];
        #pragma unroll
        for (int i = 0; i < NCHUNK; ++i)
            acc += partial[((size_t)i*BB + b)*NC + c];
        out[t] = acc;
    } else if (t == 640) {
        out[BB*NC] = (red[0] + red[1]) *
                     (LAM / (float)(NF*(NF-1)) / (float)BB * 0.125f);
    }
}

extern "C" void kernel_launch(void* const* d_in, const int* in_sizes, int n_in,
                              void* d_out, int out_size, void* d_ws, size_t ws_size,
                              hipStream_t stream) {
    const float* x     = (const float*)d_in[0];  // [16,14,14,14]
    const float* theta = (const float*)d_in[1];  // [4,1,6,3]
    const float* W     = (const float*)d_in[2];  // [40,41472]
    const float* bias  = (const float*)d_in[3];  // [40]
    float* out = (float*)d_out;                  // [640 logits][1 loss]

    float* feats   = (float*)d_ws;                       // BB*FEAT_LEN
    float* ip2     = feats + (size_t)BB * FEAT_LEN;      // NWAVE_IP2
    float* partial = ip2 + NWAVE_IP2;                    // NCHUNK*BB*NC

    sim_kernel<<<2*PP, 256, 0, stream>>>(x, theta, feats, ip2);
    logitsA<<<dim3(NCHUNK, CTILES), 128, 0, stream>>>(feats, W, partial);
    finalize_kernel<<<1, 768, 0, stream>>>(partial, bias, ip2, out);
}

// Round 14
// 37.774 us; speedup vs baseline: 1.1570x; 1.0067x over previous
//
#include <hip/hip_runtime.h>

// Problem constants (from reference)
#define NQ 6
#define NF 4
#define GG 14
#define GG2 196
#define GG3 2744
#define NSIDE 12
#define PP 1728          // NSIDE^3
#define NC 40
#define BB 16
#define LAM 0.1f
#define FEAT_LEN (NF*PP*NQ)   // 41472
#define KCH 512
#define NCHUNK 81             // 41472 / 512
#define CTILES 5              // 40 / 8
#define NWAVE_IP2 (PP*4)      // 6912 = 128*54

template<int CTRL>
__device__ __forceinline__ float fdpp(float v) {
    return __int_as_float(__builtin_amdgcn_mov_dpp(__float_as_int(v), CTRL, 0xF, 0xF, true));
}
#define DPP1(v) fdpp<0xB1>(v)   // quad_perm xor1 (VALU)
#define DPP2(v) fdpp<0x4E>(v)   // quad_perm xor2 (VALU)

// ---------- sim: 8 lanes per circuit, 8 amps per lane, 2 circuits per thread ----------
// lane = [b5=c][b4b3=f][b2=q0][b1=q4][b0=q2] ; reg l = [bit2=q1][bit1=q3][bit0=q5]
// Thread handles b0 = w*2+c and b1 = b0+8 (same f, same lane geometry -> shared
// coefficients, 2x independent FMA chains per gate for ILP).
// block = 256 thr = 4 waves = one patch p; grid = PP.

__global__ __launch_bounds__(256) void sim_kernel(
    const float* __restrict__ x,      // [B,14,14,14]
    const float* __restrict__ theta,  // [NF,1,6,3]
    float* __restrict__ feats,        // [B][NF][PP][NQ]
    float* __restrict__ ip2)          // [NWAVE_IP2]
{
    const int t = threadIdx.x;
    const int w = t >> 6, lane = t & 63;
    const int c   = lane >> 5;
    const int f   = (lane >> 3) & 3;
    const int gq0 = (lane >> 2) & 1;
    const int gq4 = (lane >> 1) & 1;
    const int gq2 = lane & 1;
    const int p   = blockIdx.x;
    const int b0  = w*2 + c;          // 0..7
    const int b1  = b0 + 8;           // 8..15

    __shared__ __align__(16) float scrot[NF*NQ][8];   // 24 CRot 2x2 matrices
    __shared__ __align__(16) float scomp[BB][NQ][4];  // composed enc columns

    const int px = p/(NSIDE*NSIDE), py = (p/NSIDE)%NSIDE, pz = p%NSIDE;

    // threads 96..119: CRot matrices (block-invariant)
    if (t >= 96 && t < 96 + NF*NQ) {
        const int j = t - 96;
        const float* a = theta + j*3;
        float s, cc, sap, cap, sam, cam;
        __sincosf(0.5f*a[1], &s, &cc);
        __sincosf(0.5f*(a[0]+a[2]), &sap, &cap);
        __sincosf(0.5f*(a[0]-a[2]), &sam, &cam);
        scrot[j][0] =  cap*cc; scrot[j][1] = -sap*cc;
        scrot[j][2] = -cam*s;  scrot[j][3] = -sam*s;
        scrot[j][4] =  cam*s;  scrot[j][5] = -sam*s;
        scrot[j][6] =  cap*cc; scrot[j][7] =  sap*cc;
    }
    // threads 0..95: composed encoding columns for all (b2, q)
    if (t < BB*NQ) {
        const int b2 = t / NQ, q = t % NQ;
        const float* xp = x + (size_t)b2*GG3 + px*GG2 + py*GG + pz;
        #define SPV(i) xp[((i)/9)*GG2 + (((i)/3)%3)*GG + ((i)%3)]
        float s, cc, sap, cap, sam, cam;
        __sincosf(0.5f*SPV(3*q+1), &s, &cc);
        __sincosf(0.5f*(SPV(3*q)+SPV(3*q+2)), &sap, &cap);
        __sincosf(0.5f*(SPV(3*q)-SPV(3*q+2)), &sam, &cam);
        float c0r = cap*cc, c0i = -sap*cc, c1r = cam*s, c1i = -sam*s;
        if (q < 3) {   // compose with gate q+6 (applied second)
            const int k2 = 3*(q+6);
            float s_,c_,sap_,cap_,sam_,cam_;
            __sincosf(0.5f*SPV(k2+1), &s_, &c_);
            __sincosf(0.5f*(SPV(k2)+SPV(k2+2)), &sap_, &cap_);
            __sincosf(0.5f*(SPV(k2)-SPV(k2+2)), &sam_, &cam_);
            float b00r=cap_*c_, b00i=-sap_*c_, b01r=-cam_*s_, b01i=-sam_*s_;
            float b10r=cam_*s_, b10i=-sam_*s_, b11r=cap_*c_,  b11i= sap_*c_;
            float n0r = b00r*c0r - b00i*c0i + b01r*c1r - b01i*c1i;
            float n0i = b00r*c0i + b00i*c0r + b01r*c1i + b01i*c1r;
            float n1r = b10r*c0r - b10i*c0i + b11r*c1r - b11i*c1i;
            float n1i = b10r*c0i + b10i*c0r + b11r*c1i + b11i*c1r;
            c0r=n0r; c0i=n0i; c1r=n1r; c1i=n1i;
        }
        #undef SPV
        scomp[b2][q][0]=c0r; scomp[b2][q][1]=c0i;
        scomp[b2][q][2]=c1r; scomp[b2][q][3]=c1i;
    }
    __syncthreads();

    float ar[2][8], ai[2][8];

    // ---- encoding: product state, per circuit u (b = b0 or b1)
    #pragma unroll
    for (int u = 0; u < 2; ++u) {
        const int bl = u ? b1 : b0;
        float4 C0 = *(const float4*)&scomp[bl][0][0];
        float4 C2 = *(const float4*)&scomp[bl][2][0];
        float4 C4 = *(const float4*)&scomp[bl][4][0];
        float e0r = gq0 ? C0.z : C0.x, e0i = gq0 ? C0.w : C0.y;
        float e2r = gq2 ? C2.z : C2.x, e2i = gq2 ? C2.w : C2.y;
        float e4r = gq4 ? C4.z : C4.x, e4i = gq4 ? C4.w : C4.y;
        float t02r = e0r*e2r - e0i*e2i, t02i = e0r*e2i + e0i*e2r;
        float pfr = t02r*e4r - t02i*e4i, pfi = t02r*e4i + t02i*e4r;
        float4 C1 = *(const float4*)&scomp[bl][1][0];
        float4 C3 = *(const float4*)&scomp[bl][3][0];
        float4 C5 = *(const float4*)&scomp[bl][5][0];
        // q1 spread (reg bit2) from {0}
        ar[u][4] = C1.z*pfr - C1.w*pfi;  ai[u][4] = C1.z*pfi + C1.w*pfr;
        ar[u][0] = C1.x*pfr - C1.y*pfi;  ai[u][0] = C1.x*pfi + C1.y*pfr;
        // q3 spread (reg bit1) on {0,4}
        #pragma unroll
        for (int l = 0; l <= 4; l += 4) {
            float r0 = ar[u][l], i0 = ai[u][l];
            ar[u][l+2] = C3.z*r0 - C3.w*i0;  ai[u][l+2] = C3.z*i0 + C3.w*r0;
            ar[u][l]   = C3.x*r0 - C3.y*i0;  ai[u][l]   = C3.x*i0 + C3.y*r0;
        }
        // q5 spread (reg bit0) on {0,2,4,6}
        #pragma unroll
        for (int l = 0; l <= 6; l += 2) {
            float r0 = ar[u][l], i0 = ai[u][l];
            ar[u][l+1] = C5.z*r0 - C5.w*i0;  ai[u][l+1] = C5.z*i0 + C5.w*r0;
            ar[u][l]   = C5.x*r0 - C5.y*i0;  ai[u][l]   = C5.x*i0 + C5.y*r0;
        }
    }

    const float4* crp = (const float4*)&scrot[f*NQ][0];

    // CR0: ctrl q0(lane b2), tgt q1(reg bit2): local pairs (l,l+4); identity if !gq0
    {
        float4 A = crp[0], Bq = crp[1];
        if (!gq0) { A = make_float4(1.f,0.f,0.f,0.f); Bq = make_float4(0.f,0.f,1.f,0.f); }
        #pragma unroll
        for (int u = 0; u < 2; ++u)
        #pragma unroll
        for (int l = 0; l < 4; ++l) {
            const int l1 = l + 4;
            float a0r=ar[u][l], a0i=ai[u][l], a1r=ar[u][l1], a1i=ai[u][l1];
            ar[u][l]  = A.x*a0r - A.y*a0i + A.z*a1r - A.w*a1i;
            ai[u][l]  = A.x*a0i + A.y*a0r + A.z*a1i + A.w*a1r;
            ar[u][l1] = Bq.x*a0r - Bq.y*a0i + Bq.z*a1r - Bq.w*a1i;
            ai[u][l1] = Bq.x*a0i + Bq.y*a0r + Bq.z*a1i + Bq.w*a1r;
        }
    }
    // CR1: ctrl q1(reg bit2 -> l=4..7), tgt q2(lane b0) -> DPP xor1
    {
        float4 A = crp[2], Bq = crp[3];
        float cAr = gq2 ? Bq.z : A.x, cAi = gq2 ? Bq.w : A.y;
        float cBr = gq2 ? Bq.x : A.z, cBi = gq2 ? Bq.y : A.w;
        #pragma unroll
        for (int u = 0; u < 2; ++u)
        #pragma unroll
        for (int l = 4; l < 8; ++l) {
            float prr = DPP1(ar[u][l]), pri = DPP1(ai[u][l]);
            float nr = cAr*ar[u][l] - cAi*ai[u][l] + cBr*prr - cBi*pri;
            float ni = cAr*ai[u][l] + cAi*ar[u][l] + cBr*pri + cBi*prr;
            ar[u][l] = nr; ai[u][l] = ni;
        }
    }
    // CR2: ctrl q2(lane b0), tgt q3(reg bit1): pairs (l,l+2), identity if !gq2
    {
        float4 A = crp[4], Bq = crp[5];
        if (!gq2) { A = make_float4(1.f,0.f,0.f,0.f); Bq = make_float4(0.f,0.f,1.f,0.f); }
        #pragma unroll
        for (int u = 0; u < 2; ++u)
        #pragma unroll
        for (int li = 0; li < 4; ++li) {
            const int l = (li & 1) | ((li & 2) << 1);   // 0,1,4,5
            const int l1 = l + 2;
            float a0r=ar[u][l], a0i=ai[u][l], a1r=ar[u][l1], a1i=ai[u][l1];
            ar[u][l]  = A.x*a0r - A.y*a0i + A.z*a1r - A.w*a1i;
            ai[u][l]  = A.x*a0i + A.y*a0r + A.z*a1i + A.w*a1r;
            ar[u][l1] = Bq.x*a0r - Bq.y*a0i + Bq.z*a1r - Bq.w*a1i;
            ai[u][l1] = Bq.x*a0i + Bq.y*a0r + Bq.z*a1i + Bq.w*a1r;
        }
    }
    // CR3: ctrl q3(reg bit1 -> l in {2,3,6,7}), tgt q4(lane b1) -> DPP xor2
    {
        float4 A = crp[6], Bq = crp[7];
        float cAr = gq4 ? Bq.z : A.x, cAi = gq4 ? Bq.w : A.y;
        float cBr = gq4 ? Bq.x : A.z, cBi = gq4 ? Bq.y : A.w;
        #pragma unroll
        for (int u = 0; u < 2; ++u)
        #pragma unroll
        for (int li = 0; li < 4; ++li) {
            const int l = 2 + (li & 1) + ((li & 2) << 1);   // 2,3,6,7
            float prr = DPP2(ar[u][l]), pri = DPP2(ai[u][l]);
            float nr = cAr*ar[u][l] - cAi*ai[u][l] + cBr*prr - cBi*pri;
            float ni = cAr*ai[u][l] + cAi*ar[u][l] + cBr*pri + cBi*prr;
            ar[u][l] = nr; ai[u][l] = ni;
        }
    }
    // CR4: ctrl q4(lane b1), tgt q5(reg bit0): pairs (l,l+1), identity if !gq4
    {
        float4 A = crp[8], Bq = crp[9];
        if (!gq4) { A = make_float4(1.f,0.f,0.f,0.f); Bq = make_float4(0.f,0.f,1.f,0.f); }
        #pragma unroll
        for (int u = 0; u < 2; ++u)
        #pragma unroll
        for (int l = 0; l < 8; l += 2) {
            const int l1 = l + 1;
            float a0r=ar[u][l], a0i=ai[u][l], a1r=ar[u][l1], a1i=ai[u][l1];
            ar[u][l]  = A.x*a0r - A.y*a0i + A.z*a1r - A.w*a1i;
            ai[u][l]  = A.x*a0i + A.y*a0r + A.z*a1i + A.w*a1r;
            ar[u][l1] = Bq.x*a0r - Bq.y*a0i + Bq.z*a1r - Bq.w*a1i;
            ai[u][l1] = Bq.x*a0i + Bq.y*a0r + Bq.z*a1i + Bq.w*a1r;
        }
    }
    // CR5: ctrl q5(reg bit0 -> odd l), tgt q0(lane b2) -> shfl xor4 (DS)
    {
        float4 A = crp[10], Bq = crp[11];
        float cAr = gq0 ? Bq.z : A.x, cAi = gq0 ? Bq.w : A.y;
        float cBr = gq0 ? Bq.x : A.z, cBi = gq0 ? Bq.y : A.w;
        #pragma unroll
        for (int u = 0; u < 2; ++u)
        #pragma unroll
        for (int l = 1; l < 8; l += 2) {
            float prr = __shfl_xor(ar[u][l], 4), pri = __shfl_xor(ai[u][l], 4);
            float nr = cAr*ar[u][l] - cAi*ai[u][l] + cBr*prr - cBi*pri;
            float ni = cAr*ai[u][l] + cAi*ar[u][l] + cBr*pri + cBi*prr;
            ar[u][l] = nr; ai[u][l] = ni;
        }
    }

    // ---- probabilities
    float pr[2][8];
    #pragma unroll
    for (int u = 0; u < 2; ++u)
    #pragma unroll
    for (int l = 0; l < 8; ++l) pr[u][l] = ar[u][l]*ar[u][l] + ai[u][l]*ai[u][l];

    // ---- loss pair-dots (per circuit): f-partners at lane-xor 8,16,24
    float lc = 0.f;
    #pragma unroll
    for (int xi = 1; xi <= 3; ++xi) {
        const int xm = xi << 3;
        #pragma unroll
        for (int u = 0; u < 2; ++u) {
            float d = 0.f;
            #pragma unroll
            for (int l = 0; l < 8; ++l) d += pr[u][l] * __shfl_xor(pr[u][l], xm);
            d += DPP1(d);
            d += DPP2(d);
            d += __shfl_xor(d, 4);
            lc += d*d;
        }
    }
    lc += DPP1(lc);
    lc += DPP2(lc);
    lc += __shfl_xor(lc, 4);
    lc += __shfl_xor(lc, 8);
    lc += __shfl_xor(lc, 16);
    lc += __shfl_xor(lc, 32);
    if (lane == 0) ip2[blockIdx.x*4 + w] = lc;   // 8x-counted; finalize /8

    // ---- expvals per circuit: reg-local signed sums (q1,q3,q5), lane signs (q0,q2,q4)
    #pragma unroll
    for (int u = 0; u < 2; ++u) {
        float eq1 = (pr[u][0]+pr[u][1]+pr[u][2]+pr[u][3]) - (pr[u][4]+pr[u][5]+pr[u][6]+pr[u][7]);
        float eq3 = (pr[u][0]+pr[u][1]+pr[u][4]+pr[u][5]) - (pr[u][2]+pr[u][3]+pr[u][6]+pr[u][7]);
        float eq5 = (pr[u][0]+pr[u][2]+pr[u][4]+pr[u][6]) - (pr[u][1]+pr[u][3]+pr[u][5]+pr[u][7]);
        float s   = (pr[u][0]+pr[u][1]+pr[u][2]+pr[u][3]) + (pr[u][4]+pr[u][5]+pr[u][6]+pr[u][7]);
        float eq0 = gq0 ? -s : s;
        float eq2 = gq2 ? -s : s;
        float eq4 = gq4 ? -s : s;
        #define GRED(e) { e += DPP1(e); e += DPP2(e); e += __shfl_xor(e, 4); }
        GRED(eq0) GRED(eq1) GRED(eq2) GRED(eq3) GRED(eq4) GRED(eq5)
        #undef GRED
        if ((lane & 7) == 0) {        // one lane per (c,f)
            const int b = u ? b1 : b0;
            float* fo = feats + (((size_t)b*NF + f)*PP + p)*NQ;
            fo[0]=eq0; fo[1]=eq1; fo[2]=eq2; fo[3]=eq3; fo[4]=eq4; fo[5]=eq5;
        }
    }
}

// ---------- logits phase A: K-split, W read once ----------

__global__ __launch_bounds__(128) void logitsA(
    const float* __restrict__ feats,   // [BB][FEAT_LEN]
    const float* __restrict__ W,       // [NC][FEAT_LEN]
    float* __restrict__ partial)       // [NCHUNK][BB][NC]
{
    const int chunk = blockIdx.x;      // 0..80
    const int ctile = blockIdx.y;      // 0..4
    const int t = threadIdx.x;         // 128
    const int jbase = chunk * KCH;

    __shared__ __align__(16) float fs[BB][KCH + 4];

    #pragma unroll
    for (int i = 0; i < 16; ++i) {
        const int gi = i*128 + t;
        const int br = gi >> 7;
        const int c4 = gi & 127;
        float4 v = *(const float4*)(feats + (size_t)br*FEAT_LEN + jbase + c4*4);
        *(float4*)&fs[br][c4*4] = v;
    }
    __syncthreads();

    const int cl = t >> 4, b = t & 15;
    const int c = ctile*8 + cl;
    const float* wr = W + (size_t)c*FEAT_LEN + jbase;
    float acc = 0.f;
    #pragma unroll 8
    for (int j4 = 0; j4 < KCH/4; ++j4) {
        float4 wv = *(const float4*)(wr + j4*4);
        float4 fv = *(const float4*)&fs[b][j4*4];
        acc += wv.x*fv.x + wv.y*fv.y + wv.z*fv.z + wv.w*fv.w;
    }
    partial[((size_t)chunk*BB + b)*NC + c] = acc;
}

// ---------- phase B: logits reduce + bias (coalesced), loss reduce (unrolled) ----------

__global__ __launch_bounds__(768) void finalize_kernel(
    const float* __restrict__ partial, const float* __restrict__ bias,
    const float* __restrict__ ip2, float* __restrict__ out)
{
    const int t = threadIdx.x;
    __shared__ float red[2];

    if (t >= 640) {
        const int idx = t - 640;       // 128 threads, 54 strided loads each
        float acc = 0.f;
        #pragma unroll
        for (int k = 0; k < 54; ++k) acc += ip2[idx + k*128];
        #pragma unroll
        for (int m = 1; m < 64; m <<= 1) acc += __shfl_xor(acc, m);
        if ((idx & 63) == 0) red[idx >> 6] = acc;
    }
    __syncthreads();

    if (t < BB*NC) {
        const int b = t / NC, c = t % NC;   // consecutive t -> consecutive c
        float acc = bias[c];
        #pragma unroll
        for (int i = 0; i < NCHUNK; ++i)
            acc += partial[((size_t)i*BB + b)*NC + c];
        out[t] = acc;
    } else if (t == 640) {
        out[BB*NC] = (red[0] + red[1]) *
                     (LAM / (float)(NF*(NF-1)) / (float)BB * 0.125f);
    }
}

extern "C" void kernel_launch(void* const* d_in, const int* in_sizes, int n_in,
                              void* d_out, int out_size, void* d_ws, size_t ws_size,
                              hipStream_t stream) {
    const float* x     = (const float*)d_in[0];  // [16,14,14,14]
    const float* theta = (const float*)d_in[1];  // [4,1,6,3]
    const float* W     = (const float*)d_in[2];  // [40,41472]
    const float* bias  = (const float*)d_in[3];  // [40]
    float* out = (float*)d_out;                  // [640 logits][1 loss]

    float* feats   = (float*)d_ws;                       // BB*FEAT_LEN
    float* ip2     = feats + (size_t)BB * FEAT_LEN;      // NWAVE_IP2
    float* partial = ip2 + NWAVE_IP2;                    // NCHUNK*BB*NC

    sim_kernel<<<PP, 256, 0, stream>>>(x, theta, feats, ip2);
    logitsA<<<dim3(NCHUNK, CTILES), 128, 0, stream>>>(feats, W, partial);
    finalize_kernel<<<1, 768, 0, stream>>>(partial, bias, ip2, out);
}